// Round 10
// baseline (97.716 us; speedup 1.0000x reference)
//
#include <hip/hip_runtime.h>
#include <math.h>

#define NUM_ENTITY 100000
#define NUM_TYPE   5000
#define DIM        128
#define BATCH      512
#define MARGIN     2.0f

#define TG 64       // types per wave (one per lane)
#define BG 8        // batch rows per wave
#define TSTRIDE 68  // t-tile row stride in dwords (64 + 4; 16B-aligned, uniform bank spread)

typedef _Float16 half_t;
typedef half_t half2_t __attribute__((ext_vector_type(2)));

// r9 regression root-cause: per-lane typ gather was stride-512B -> every load
// touched 64 cache lines -> ~660 MB L2 traffic (~19us of L2 BW). The 1-wave
// barrier-free structure was fine. This round keeps it but routes the
// row->lane transpose through LDS: coalesced typ reads -> f16 -> [64][68]dw
// tile -> each lane fills tf[16] from its own row (both patterns verified
// uniform 8 dword-accesses/bank = conflict-free). e stays as 2KB broadcast
// tile. No barriers beyond one waitcnt-equivalent syncthreads, no reduce.
__device__ __forceinline__ uint32_t pk2(float x, float y) {
    return __builtin_bit_cast(uint32_t, __builtin_amdgcn_cvt_pkrtz(x, y));
}

__device__ __forceinline__ float absdot(uint32_t eu, uint32_t tu, float acc) {
    const half2_t ones = {(half_t)1.0f, (half_t)1.0f};
    half2_t d = __builtin_bit_cast(half2_t, eu) - __builtin_bit_cast(half2_t, tu);
    const uint32_t du = __builtin_bit_cast(uint32_t, d) & 0x7fff7fffu;
#if __has_builtin(__builtin_amdgcn_fdot2)
    return __builtin_amdgcn_fdot2(__builtin_bit_cast(half2_t, du), ones, acc, false);
#else
    half2_t a = __builtin_bit_cast(half2_t, du);
    return acc + (float)a[0] + (float)a[1];
#endif
}

__global__ __launch_bounds__(64) void l1dist_sigmoid_kernel(
    const float* __restrict__ ent,
    const float* __restrict__ typ,
    const int*   __restrict__ xb,
    float*       __restrict__ out)
{
    __shared__ uint32_t tL[TG * TSTRIDE];   // 17408 B, packed f16
    __shared__ uint32_t eL[BG * 64];        //  2048 B, packed f16

    const int l  = threadIdx.x;             // 0..63
    const int t0 = blockIdx.x * TG;
    const int b0 = blockIdx.y * BG;

    // ---- stage t tile COALESCED: 64 rows x 32 float4; g = l + 64s ->
    // row = g>>5 (2 waves' worth of lanes per row... 32 f4/row), c4 = g&31.
    // unroll 8 caps in-flight load regs (~32) while keeping 8-deep VMEM.
#pragma unroll 8
    for (int s = 0; s < 32; ++s) {
        const int g   = l + 64 * s;
        const int row = g >> 5;
        const int c4  = g & 31;
        const int tr  = min(t0 + row, NUM_TYPE - 1);
        const float4 v = *(const float4*)&typ[tr * DIM + c4 * 4];
        uint2 w;
        w.x = pk2(v.x, v.y);
        w.y = pk2(v.z, v.w);
        *(uint2*)&tL[row * TSTRIDE + c4 * 2] = w;
    }

    // ---- stage e rows f32->f16: 8 rows x 32 float4, 4 per lane
#pragma unroll
    for (int s = 0; s < 4; ++s) {
        const int g   = l + 64 * s;
        const int row = g >> 5;
        const int c4  = g & 31;
        const int er  = xb[b0 + row];
        const float4 v = *(const float4*)&ent[er * DIM + c4 * 4];
        uint2 w;
        w.x = pk2(v.x, v.y);
        w.y = pk2(v.z, v.w);
        *(uint2*)&eL[row * 64 + c4 * 2] = w;
    }

    __syncthreads();   // single-wave block: compiles to a waitcnt

    // ---- own type row LDS -> registers (16 x ds_read_b128, conflict-free)
    uint4 tf[16];
#pragma unroll
    for (int c = 0; c < 16; ++c)
        tf[c] = *(const uint4*)&tL[l * TSTRIDE + c * 4];

    const bool valid = (t0 + l) < NUM_TYPE;

    // ---- compute: 8 b-rows; e read as wave-uniform broadcast b128
#pragma unroll 1
    for (int i = 0; i < BG; ++i) {
        float acc = 0.0f;
#pragma unroll 8
        for (int c = 0; c < 16; ++c) {
            const uint4 ev = *(const uint4*)&eL[i * 64 + c * 4];
            acc = absdot(ev.x, tf[c].x, acc);
            acc = absdot(ev.y, tf[c].y, acc);
            acc = absdot(ev.z, tf[c].z, acc);
            acc = absdot(ev.w, tf[c].w, acc);
        }
        if (valid) {
            const float x = MARGIN - acc;
            out[(b0 + i) * NUM_TYPE + t0 + l] = 1.0f / (1.0f + __expf(-x));
        }
    }
}

extern "C" void kernel_launch(void* const* d_in, const int* in_sizes, int n_in,
                              void* d_out, int out_size, void* d_ws, size_t ws_size,
                              hipStream_t stream) {
    const float* ent = (const float*)d_in[0];
    const float* typ = (const float*)d_in[1];
    const int*   xb  = (const int*)d_in[2];
    float*       out = (float*)d_out;

    dim3 grid((NUM_TYPE + TG - 1) / TG, BATCH / BG);  // (79, 64) = 5056 one-wave blocks
    dim3 block(64);
    l1dist_sigmoid_kernel<<<grid, block, 0, stream>>>(ent, typ, xb, out);
}

// Round 11
// 30.495 us; speedup vs baseline: 3.2043x; 3.2043x over previous
//
#include <hip/hip_runtime.h>
#include <math.h>

#define NUM_ENTITY 100000
#define NUM_TYPE   5000
#define DIM        128
#define BATCH      512
#define MARGIN     2.0f

#define TG 64       // types per wave (one per lane)
#define BG 8        // batch rows per wave
#define TSTRIDE 68  // t-tile row stride in dwords (64 + 4; 16B-aligned, 2-way max bank aliasing)

typedef _Float16 half_t;
typedef half_t half2_t __attribute__((ext_vector_type(2)));

// r10 post-mortem: design was right, allocator wasn't. With bare
// __launch_bounds__(64) hipcc chose an 88-VGPR occupancy target and spilled
// tf[16] (64 VGPR) to scratch: 83 MB scratch writes (= WRITE_SIZE delta),
// 8x re-read -> 97us. Residency here is LDS-capped at 8 blocks/CU
// (19.5 KB/block) = 2 waves/SIMD regardless of VGPRs, so (64,1) releases
// the register budget AT ZERO occupancy cost. Nothing else changed vs r10.
__device__ __forceinline__ uint32_t pk2(float x, float y) {
    return __builtin_bit_cast(uint32_t, __builtin_amdgcn_cvt_pkrtz(x, y));
}

__device__ __forceinline__ float absdot(uint32_t eu, uint32_t tu, float acc) {
    const half2_t ones = {(half_t)1.0f, (half_t)1.0f};
    half2_t d = __builtin_bit_cast(half2_t, eu) - __builtin_bit_cast(half2_t, tu);
    const uint32_t du = __builtin_bit_cast(uint32_t, d) & 0x7fff7fffu;
#if __has_builtin(__builtin_amdgcn_fdot2)
    return __builtin_amdgcn_fdot2(__builtin_bit_cast(half2_t, du), ones, acc, false);
#else
    half2_t a = __builtin_bit_cast(half2_t, du);
    return acc + (float)a[0] + (float)a[1];
#endif
}

__global__ __launch_bounds__(64, 1) void l1dist_sigmoid_kernel(
    const float* __restrict__ ent,
    const float* __restrict__ typ,
    const int*   __restrict__ xb,
    float*       __restrict__ out)
{
    __shared__ uint32_t tL[TG * TSTRIDE];   // 17408 B, packed f16
    __shared__ uint32_t eL[BG * 64];        //  2048 B, packed f16

    const int l  = threadIdx.x;             // 0..63
    const int t0 = blockIdx.x * TG;
    const int b0 = blockIdx.y * BG;

    // ---- stage e rows first (tiny, issues early): 8 rows x 32 float4
#pragma unroll
    for (int s = 0; s < 4; ++s) {
        const int g   = l + 64 * s;
        const int row = g >> 5;
        const int c4  = g & 31;
        const int er  = xb[b0 + row];
        const float4 v = *(const float4*)&ent[er * DIM + c4 * 4];
        uint2 w;
        w.x = pk2(v.x, v.y);
        w.y = pk2(v.z, v.w);
        *(uint2*)&eL[row * 64 + c4 * 2] = w;
    }

    // ---- stage t tile COALESCED: 64 rows x 32 float4; g = l + 64s ->
    // row = g>>5, c4 = g&31. unroll 8 keeps 8-deep VMEM in flight.
#pragma unroll 8
    for (int s = 0; s < 32; ++s) {
        const int g   = l + 64 * s;
        const int row = g >> 5;
        const int c4  = g & 31;
        const int tr  = min(t0 + row, NUM_TYPE - 1);
        const float4 v = *(const float4*)&typ[tr * DIM + c4 * 4];
        uint2 w;
        w.x = pk2(v.x, v.y);
        w.y = pk2(v.z, v.w);
        *(uint2*)&tL[row * TSTRIDE + c4 * 2] = w;
    }

    __syncthreads();   // single-wave block: compiles to a waitcnt

    // ---- own type row LDS -> registers (16 x ds_read_b128)
    uint4 tf[16];
#pragma unroll
    for (int c = 0; c < 16; ++c)
        tf[c] = *(const uint4*)&tL[l * TSTRIDE + c * 4];

    const bool valid = (t0 + l) < NUM_TYPE;

    // ---- compute: 8 b-rows; e read as wave-uniform broadcast b128
#pragma unroll 1
    for (int i = 0; i < BG; ++i) {
        float acc = 0.0f;
#pragma unroll
        for (int c = 0; c < 16; ++c) {
            const uint4 ev = *(const uint4*)&eL[i * 64 + c * 4];
            acc = absdot(ev.x, tf[c].x, acc);
            acc = absdot(ev.y, tf[c].y, acc);
            acc = absdot(ev.z, tf[c].z, acc);
            acc = absdot(ev.w, tf[c].w, acc);
        }
        if (valid) {
            const float x = MARGIN - acc;
            out[(b0 + i) * NUM_TYPE + t0 + l] = 1.0f / (1.0f + __expf(-x));
        }
    }
}

extern "C" void kernel_launch(void* const* d_in, const int* in_sizes, int n_in,
                              void* d_out, int out_size, void* d_ws, size_t ws_size,
                              hipStream_t stream) {
    const float* ent = (const float*)d_in[0];
    const float* typ = (const float*)d_in[1];
    const int*   xb  = (const int*)d_in[2];
    float*       out = (float*)d_out;

    dim3 grid((NUM_TYPE + TG - 1) / TG, BATCH / BG);  // (79, 64) = 5056 one-wave blocks
    dim3 block(64);
    l1dist_sigmoid_kernel<<<grid, block, 0, stream>>>(ent, typ, xb, out);
}